// Round 5
// baseline (232.237 us; speedup 1.0000x reference)
//
#include <hip/hip_runtime.h>
#include <hip/hip_bf16.h>
#include <stdint.h>

typedef __attribute__((ext_vector_type(8))) short bf16x8;
typedef __attribute__((ext_vector_type(4))) float f32x4;

__device__ __forceinline__ unsigned short f2bf(float f) {
  __hip_bfloat16 h = __float2bfloat16(f);
  return *reinterpret_cast<unsigned short*>(&h);
}

// ---------------- absmax over both weights (gridDim.y = tensor id) ----------------
__global__ void absmax2_kernel(const float* __restrict__ w1, const float* __restrict__ w2,
                               int n4, unsigned int* __restrict__ out) {
  const float* w = blockIdx.y ? w2 : w1;
  __shared__ unsigned int red[256];
  unsigned int m = 0u;
  const uint4* w4 = reinterpret_cast<const uint4*>(w);
  for (int i = blockIdx.x * blockDim.x + threadIdx.x; i < n4;
       i += gridDim.x * blockDim.x) {
    uint4 v = w4[i];
    m = max(m, v.x & 0x7fffffffu);
    m = max(m, v.y & 0x7fffffffu);
    m = max(m, v.z & 0x7fffffffu);
    m = max(m, v.w & 0x7fffffffu);
  }
  red[threadIdx.x] = m;
  __syncthreads();
  for (int s = 128; s > 0; s >>= 1) {
    if ((int)threadIdx.x < s)
      red[threadIdx.x] = max(red[threadIdx.x], red[threadIdx.x + s]);
    __syncthreads();
  }
  if (threadIdx.x == 0) atomicMax(out + blockIdx.y, red[0]);
}

// ---------------- fused: fake-quant w1/w2 (y=0/1) + cast x (y=2), all -> bf16 ----------------
__global__ void quantcast_kernel(const float* __restrict__ w1, const float* __restrict__ w2,
                                 const float* __restrict__ x,
                                 int n4w, int n4x,
                                 const unsigned int* __restrict__ maxbits,
                                 const int* __restrict__ bits,
                                 unsigned short* __restrict__ o1,
                                 unsigned short* __restrict__ o2,
                                 unsigned short* __restrict__ ox) {
  if (blockIdx.y == 2) {
    const float4* x4 = reinterpret_cast<const float4*>(x);
    ushort4* o4 = reinterpret_cast<ushort4*>(ox);
    for (int i = blockIdx.x * blockDim.x + threadIdx.x; i < n4x;
         i += gridDim.x * blockDim.x) {
      float4 v = x4[i];
      o4[i] = make_ushort4(f2bf(v.x), f2bf(v.y), f2bf(v.z), f2bf(v.w));
    }
    return;
  }
  const float* w = blockIdx.y ? w2 : w1;
  unsigned short* o = blockIdx.y ? o2 : o1;
  const float qmax = (float)((1 << (*bits - 1)) - 1);
  const float scale = __uint_as_float(maxbits[blockIdx.y]) / qmax;
  const float4* w4 = reinterpret_cast<const float4*>(w);
  ushort4* o4 = reinterpret_cast<ushort4*>(o);
  for (int i = blockIdx.x * blockDim.x + threadIdx.x; i < n4w;
       i += gridDim.x * blockDim.x) {
    float4 v = w4[i];
    float a = fminf(fmaxf(rintf(v.x / scale), -qmax), qmax) * scale;
    float b = fminf(fmaxf(rintf(v.y / scale), -qmax), qmax) * scale;
    float c = fminf(fmaxf(rintf(v.z / scale), -qmax), qmax) * scale;
    float d = fminf(fmaxf(rintf(v.w / scale), -qmax), qmax) * scale;
    o4[i] = make_ushort4(f2bf(a), f2bf(b), f2bf(c), f2bf(d));
  }
}

// ---------------- bf16 GEMM, C[M,N] = A[M,K] * B[N,K]^T + bias, optional ReLU ----------------
// Occupancy-first variant: BK=32 halves LDS (GEMM1 32KB -> 5 blocks/CU,
// GEMM2 24KB -> 6 blocks/CU) for TLP latency hiding. dbuf + 2-deep issue +
// COUNTED vmcnt kept from round 4. Swizzle: 4 slots/row, slot ^= (row>>1)&3
// (16-lane read groups spread over 8 bank-groups = 2-way = free).
template<int BM, int MINW, bool RELU, bool BF16_OUT>
__global__ __launch_bounds__(256, MINW)
void gemm_bt(const unsigned short* __restrict__ A,  // [M,K] bf16 bits
             const unsigned short* __restrict__ B,  // [N,K] bf16 bits
             const float* __restrict__ bias,        // [N]
             void* __restrict__ Cout,               // [M,N] bf16 or f32
             int M, int N, int K, int gx) {
  constexpr int BK = 32;
  constexpr int MF = BM / 32;    // A-frags per wave
  __shared__ __attribute__((aligned(16))) unsigned short As[2][BM * BK];
  __shared__ __attribute__((aligned(16))) unsigned short Bs[2][128 * BK];

  // bijective XCD swizzle (T1/m204)
  const int nwg = gridDim.x;
  const int orig = blockIdx.x;
  const int q = nwg >> 3, r = nwg & 7;
  const int xcd = orig & 7, cidx = orig >> 3;
  const int wgid = (xcd < r ? xcd * (q + 1) : r * (q + 1) + (xcd - r) * q) + cidx;
  const int bx = wgid % gx;
  const int by = wgid / gx;

  const int tid = threadIdx.x;
  const int lane = tid & 63;
  const int wave = tid >> 6;
  const int wr = wave >> 1;
  const int wc = wave & 1;
  const long brow = (long)by * BM;
  const long bcol = (long)bx * 128;

  f32x4 acc[MF][4] = {};

  // staging: chunk = 16 rows x 32 elems (1KB); lane -> row lane>>2, slot lane&3
  // global slot pre-swizzled: (lane&3) ^ ((row>>1)&3) = (lane&3) ^ ((lane>>3)&3)
  const int srow = lane >> 2;
  const int gslot = ((lane & 3) ^ ((lane >> 3) & 3)) * 8;
  const int fr = lane & 15;
  const int fs = lane >> 4;   // logical 16B k-slot (0..3)

  auto stage = [&](int k0, int b) {
#pragma unroll
    for (int it = 0; it < BM / 64; ++it) {
      const int c = it * 4 + wave;
      const unsigned short* ga = A + (brow + c * 16 + srow) * (long)K + k0 + gslot;
      __builtin_amdgcn_global_load_lds(
          (const __attribute__((address_space(1))) void*)ga,
          (__attribute__((address_space(3))) void*)(&As[b][c * 512]), 16, 0, 0);
    }
#pragma unroll
    for (int it = 0; it < 2; ++it) {
      const int c = it * 4 + wave;
      const unsigned short* gb = B + (bcol + c * 16 + srow) * (long)K + k0 + gslot;
      __builtin_amdgcn_global_load_lds(
          (const __attribute__((address_space(1))) void*)gb,
          (__attribute__((address_space(3))) void*)(&Bs[b][c * 512]), 16, 0, 0);
    }
  };

  const int nt = K / BK;
  stage(0, 0);
  stage(BK, 1);

  for (int t = 0; t < nt; ++t) {
    const int b = t & 1;
    // wait for stage(t); stage(t+1)'s loads (4 or 3) stay in flight
    if (t < nt - 1) {
      if constexpr (BM == 128) asm volatile("s_waitcnt vmcnt(4)" ::: "memory");
      else                     asm volatile("s_waitcnt vmcnt(3)" ::: "memory");
    } else {
      asm volatile("s_waitcnt vmcnt(0)" ::: "memory");
    }
    __builtin_amdgcn_s_barrier();

    const unsigned short* as = &As[b][0];
    const unsigned short* bs = &Bs[b][0];
    bf16x8 a[MF], bb[4];
#pragma unroll
    for (int m = 0; m < MF; ++m) {
      const int row = wr * (MF * 16) + m * 16 + fr;
      a[m] = *reinterpret_cast<const bf16x8*>(as + row * BK + ((fs ^ ((row >> 1) & 3)) * 8));
    }
#pragma unroll
    for (int n = 0; n < 4; ++n) {
      const int row = wc * 64 + n * 16 + fr;
      bb[n] = *reinterpret_cast<const bf16x8*>(bs + row * BK + ((fs ^ ((row >> 1) & 3)) * 8));
    }
#pragma unroll
    for (int m = 0; m < MF; ++m)
#pragma unroll
      for (int n = 0; n < 4; ++n)
        acc[m][n] = __builtin_amdgcn_mfma_f32_16x16x32_bf16(a[m], bb[n], acc[m][n], 0, 0, 0);

    asm volatile("s_waitcnt lgkmcnt(0)" ::: "memory");
    __builtin_amdgcn_sched_barrier(0);
    __builtin_amdgcn_s_barrier();
    if (t + 2 < nt) stage((t + 2) * BK, b);
  }

  // epilogue: C/D layout col=lane&15, row=(lane>>4)*4+r  [m89/m91 verified]
  const int fq = lane >> 4;
#pragma unroll
  for (int n = 0; n < 4; ++n) {
    const long col = bcol + wc * 64 + n * 16 + fr;
    const float bv = bias[col];
#pragma unroll
    for (int m = 0; m < MF; ++m) {
#pragma unroll
      for (int rr = 0; rr < 4; ++rr) {
        const long row = brow + wr * (MF * 16) + m * 16 + fq * 4 + rr;
        float v = acc[m][n][rr] + bv;
        if (RELU) v = fmaxf(v, 0.0f);
        if (BF16_OUT)
          ((unsigned short*)Cout)[row * N + col] = f2bf(v);
        else
          ((float*)Cout)[row * N + col] = v;
      }
    }
  }
}

extern "C" void kernel_launch(void* const* d_in, const int* in_sizes, int n_in,
                              void* d_out, int out_size, void* d_ws, size_t ws_size,
                              hipStream_t stream) {
  const float* x  = (const float*)d_in[0];
  const float* w1 = (const float*)d_in[1];
  const float* b1 = (const float*)d_in[2];
  const float* w2 = (const float*)d_in[3];
  const float* b2 = (const float*)d_in[4];
  const int* bits = (const int*)d_in[5];

  const int M = 64 * 196;  // 12544 tokens
  const int D = 768, H = 3072;
  const int nx = M * D;
  const int nw1 = H * D;
  const int nw2 = D * H;

  char* ws = (char*)d_ws;
  unsigned int* scales = (unsigned int*)ws;
  unsigned short* xb  = (unsigned short*)(ws + 256);
  unsigned short* w1q = (unsigned short*)(ws + 256 + (size_t)nx * 2);
  unsigned short* w2q = (unsigned short*)(ws + 256 + (size_t)nx * 2 + (size_t)nw1 * 2);
  unsigned short* hb  = (unsigned short*)(ws + 256 + (size_t)nx * 2 + (size_t)(nw1 + nw2) * 2);

  hipMemsetAsync(scales, 0, 8, stream);
  absmax2_kernel<<<dim3(512, 2), 256, 0, stream>>>(w1, w2, nw1 / 4, scales);
  quantcast_kernel<<<dim3(768, 3), 256, 0, stream>>>(w1, w2, x, nw1 / 4, nx / 4,
                                                     scales, bits, w1q, w2q, xb);

  // GEMM1: h = relu(x @ w1^T + b1), [12544,3072] bf16 ; 24x98 = 2352 blocks
  gemm_bt<128, 5, true, true><<<(H / 128) * (M / 128), 256, 0, stream>>>(
      xb, w1q, b1, hb, M, H, D, H / 128);
  // GEMM2: out = h @ w2^T + b2, [12544,768] f32 ; BM=64 -> 6x196 = 1176 blocks
  gemm_bt<64, 6, false, false><<<(D / 128) * (M / 64), 256, 0, stream>>>(
      hb, w2q, b2, d_out, M, D, H, D / 128);
}

// Round 6
// 222.909 us; speedup vs baseline: 1.0418x; 1.0418x over previous
//
#include <hip/hip_runtime.h>
#include <hip/hip_bf16.h>
#include <stdint.h>

typedef __attribute__((ext_vector_type(8))) short bf16x8;
typedef __attribute__((ext_vector_type(4))) float f32x4;

__device__ __forceinline__ unsigned short f2bf(float f) {
  __hip_bfloat16 h = __float2bfloat16(f);
  return *reinterpret_cast<unsigned short*>(&h);
}

// ---------------- absmax over both weights (gridDim.y = tensor id) ----------------
__global__ void absmax2_kernel(const float* __restrict__ w1, const float* __restrict__ w2,
                               int n4, unsigned int* __restrict__ out) {
  const float* w = blockIdx.y ? w2 : w1;
  __shared__ unsigned int red[256];
  unsigned int m = 0u;
  const uint4* w4 = reinterpret_cast<const uint4*>(w);
  for (int i = blockIdx.x * blockDim.x + threadIdx.x; i < n4;
       i += gridDim.x * blockDim.x) {
    uint4 v = w4[i];
    m = max(m, v.x & 0x7fffffffu);
    m = max(m, v.y & 0x7fffffffu);
    m = max(m, v.z & 0x7fffffffu);
    m = max(m, v.w & 0x7fffffffu);
  }
  red[threadIdx.x] = m;
  __syncthreads();
  for (int s = 128; s > 0; s >>= 1) {
    if ((int)threadIdx.x < s)
      red[threadIdx.x] = max(red[threadIdx.x], red[threadIdx.x + s]);
    __syncthreads();
  }
  if (threadIdx.x == 0) atomicMax(out + blockIdx.y, red[0]);
}

// ---------------- fused: fake-quant w1/w2 (y=0/1) + cast x (y=2), all -> bf16 ----------------
__global__ void quantcast_kernel(const float* __restrict__ w1, const float* __restrict__ w2,
                                 const float* __restrict__ x,
                                 int n4w, int n4x,
                                 const unsigned int* __restrict__ maxbits,
                                 const int* __restrict__ bits,
                                 unsigned short* __restrict__ o1,
                                 unsigned short* __restrict__ o2,
                                 unsigned short* __restrict__ ox) {
  if (blockIdx.y == 2) {
    const float4* x4 = reinterpret_cast<const float4*>(x);
    ushort4* o4 = reinterpret_cast<ushort4*>(ox);
    for (int i = blockIdx.x * blockDim.x + threadIdx.x; i < n4x;
         i += gridDim.x * blockDim.x) {
      float4 v = x4[i];
      o4[i] = make_ushort4(f2bf(v.x), f2bf(v.y), f2bf(v.z), f2bf(v.w));
    }
    return;
  }
  const float* w = blockIdx.y ? w2 : w1;
  unsigned short* o = blockIdx.y ? o2 : o1;
  const float qmax = (float)((1 << (*bits - 1)) - 1);
  const float scale = __uint_as_float(maxbits[blockIdx.y]) / qmax;
  const float4* w4 = reinterpret_cast<const float4*>(w);
  ushort4* o4 = reinterpret_cast<ushort4*>(o);
  for (int i = blockIdx.x * blockDim.x + threadIdx.x; i < n4w;
       i += gridDim.x * blockDim.x) {
    float4 v = w4[i];
    float a = fminf(fmaxf(rintf(v.x / scale), -qmax), qmax) * scale;
    float b = fminf(fmaxf(rintf(v.y / scale), -qmax), qmax) * scale;
    float c = fminf(fmaxf(rintf(v.z / scale), -qmax), qmax) * scale;
    float d = fminf(fmaxf(rintf(v.w / scale), -qmax), qmax) * scale;
    o4[i] = make_ushort4(f2bf(a), f2bf(b), f2bf(c), f2bf(d));
  }
}

// ---------------- bf16 GEMM, C[M,N] = A[M,K] * B[N,K]^T + bias, optional ReLU ----------------
// Fat-wave-tile variant: block 256x128, BK=32, 4 waves (2M x 2N), wave tile
// 128x64 -> 12 ds_read_b128 per 32 MFMA per wave-iter (0.375 reads/MFMA,
// LDS pipe ~= MFMA pipe). dbuf + 2-deep issue + COUNTED vmcnt (round-4
// skeleton). Swizzle: 4 slots/row, slot ^= (row>>1)&3 on both the global
// source and the ds_read (rounds 3-5: 0 conflicts).
template<bool RELU, bool BF16_OUT>
__global__ __launch_bounds__(256, 2)
void gemm_bt(const unsigned short* __restrict__ A,  // [M,K] bf16 bits
             const unsigned short* __restrict__ B,  // [N,K] bf16 bits
             const float* __restrict__ bias,        // [N]
             void* __restrict__ Cout,               // [M,N] bf16 or f32
             int M, int N, int K, int gx) {
  constexpr int BM = 256, BN = 128, BK = 32;
  __shared__ __attribute__((aligned(16))) unsigned short As[2][BM * BK];
  __shared__ __attribute__((aligned(16))) unsigned short Bs[2][BN * BK];

  // bijective XCD swizzle (T1/m204)
  const int nwg = gridDim.x;
  const int orig = blockIdx.x;
  const int q = nwg >> 3, r = nwg & 7;
  const int xcd = orig & 7, cidx = orig >> 3;
  const int wgid = (xcd < r ? xcd * (q + 1) : r * (q + 1) + (xcd - r) * q) + cidx;
  const int bx = wgid % gx;
  const int by = wgid / gx;

  const int tid = threadIdx.x;
  const int lane = tid & 63;
  const int wave = tid >> 6;
  const int wr = wave >> 1;   // M band (2 x 128)
  const int wc = wave & 1;    // N band (2 x 64)
  const long brow = (long)by * BM;
  const long bcol = (long)bx * BN;

  f32x4 acc[8][4] = {};

  // staging: chunk = 16 rows x 32 elems (1KB); lane -> row lane>>2, slot lane&3
  // global slot pre-swizzled: (lane&3) ^ ((lane>>3)&3)
  const int srow = lane >> 2;
  const int gslot = ((lane & 3) ^ ((lane >> 3) & 3)) * 8;
  const int fr = lane & 15;
  const int fs = lane >> 4;   // logical 16B k-slot (0..3)

  auto stage = [&](int k0, int b) {
#pragma unroll
    for (int it = 0; it < 4; ++it) {          // A: 16 chunks of 16 rows
      const int c = it * 4 + wave;
      const unsigned short* ga = A + (brow + c * 16 + srow) * (long)K + k0 + gslot;
      __builtin_amdgcn_global_load_lds(
          (const __attribute__((address_space(1))) void*)ga,
          (__attribute__((address_space(3))) void*)(&As[b][c * 512]), 16, 0, 0);
    }
#pragma unroll
    for (int it = 0; it < 2; ++it) {          // B: 8 chunks
      const int c = it * 4 + wave;
      const unsigned short* gb = B + (bcol + c * 16 + srow) * (long)K + k0 + gslot;
      __builtin_amdgcn_global_load_lds(
          (const __attribute__((address_space(1))) void*)gb,
          (__attribute__((address_space(3))) void*)(&Bs[b][c * 512]), 16, 0, 0);
    }
  };

  const int nt = K / BK;
  stage(0, 0);
  stage(BK, 1);

  for (int t = 0; t < nt; ++t) {
    const int b = t & 1;
    // wait for stage(t); stage(t+1)'s 6 loads stay in flight
    if (t < nt - 1) asm volatile("s_waitcnt vmcnt(6)" ::: "memory");
    else            asm volatile("s_waitcnt vmcnt(0)" ::: "memory");
    __builtin_amdgcn_s_barrier();

    const unsigned short* as = &As[b][0];
    const unsigned short* bs = &Bs[b][0];
    bf16x8 a[8], bb[4];
#pragma unroll
    for (int m = 0; m < 8; ++m) {
      const int row = wr * 128 + m * 16 + fr;
      a[m] = *reinterpret_cast<const bf16x8*>(as + row * BK + ((fs ^ ((row >> 1) & 3)) * 8));
    }
#pragma unroll
    for (int n = 0; n < 4; ++n) {
      const int row = wc * 64 + n * 16 + fr;
      bb[n] = *reinterpret_cast<const bf16x8*>(bs + row * BK + ((fs ^ ((row >> 1) & 3)) * 8));
    }
#pragma unroll
    for (int m = 0; m < 8; ++m)
#pragma unroll
      for (int n = 0; n < 4; ++n)
        acc[m][n] = __builtin_amdgcn_mfma_f32_16x16x32_bf16(a[m], bb[n], acc[m][n], 0, 0, 0);

    asm volatile("s_waitcnt lgkmcnt(0)" ::: "memory");
    __builtin_amdgcn_sched_barrier(0);
    __builtin_amdgcn_s_barrier();
    if (t + 2 < nt) stage((t + 2) * BK, b);
  }

  // epilogue: C/D layout col=lane&15, row=(lane>>4)*4+rr  [m89/m91 verified]
  const int fq = lane >> 4;
#pragma unroll
  for (int n = 0; n < 4; ++n) {
    const long col = bcol + wc * 64 + n * 16 + fr;
    const float bv = bias[col];
#pragma unroll
    for (int m = 0; m < 8; ++m) {
#pragma unroll
      for (int rr = 0; rr < 4; ++rr) {
        const long row = brow + wr * 128 + m * 16 + fq * 4 + rr;
        float v = acc[m][n][rr] + bv;
        if (RELU) v = fmaxf(v, 0.0f);
        if (BF16_OUT)
          ((unsigned short*)Cout)[row * N + col] = f2bf(v);
        else
          ((float*)Cout)[row * N + col] = v;
      }
    }
  }
}

extern "C" void kernel_launch(void* const* d_in, const int* in_sizes, int n_in,
                              void* d_out, int out_size, void* d_ws, size_t ws_size,
                              hipStream_t stream) {
  const float* x  = (const float*)d_in[0];
  const float* w1 = (const float*)d_in[1];
  const float* b1 = (const float*)d_in[2];
  const float* w2 = (const float*)d_in[3];
  const float* b2 = (const float*)d_in[4];
  const int* bits = (const int*)d_in[5];

  const int M = 64 * 196;  // 12544 tokens
  const int D = 768, H = 3072;
  const int nx = M * D;
  const int nw1 = H * D;
  const int nw2 = D * H;

  char* ws = (char*)d_ws;
  unsigned int* scales = (unsigned int*)ws;
  unsigned short* xb  = (unsigned short*)(ws + 256);
  unsigned short* w1q = (unsigned short*)(ws + 256 + (size_t)nx * 2);
  unsigned short* w2q = (unsigned short*)(ws + 256 + (size_t)nx * 2 + (size_t)nw1 * 2);
  unsigned short* hb  = (unsigned short*)(ws + 256 + (size_t)nx * 2 + (size_t)(nw1 + nw2) * 2);

  hipMemsetAsync(scales, 0, 8, stream);
  absmax2_kernel<<<dim3(512, 2), 256, 0, stream>>>(w1, w2, nw1 / 4, scales);
  quantcast_kernel<<<dim3(768, 3), 256, 0, stream>>>(w1, w2, x, nw1 / 4, nx / 4,
                                                     scales, bits, w1q, w2q, xb);

  // GEMM1: h = relu(x @ w1^T + b1), [12544,3072] bf16 ; 49x24 = 1176 blocks
  gemm_bt<true, true><<<(M / 256) * (H / 128), 256, 0, stream>>>(
      xb, w1q, b1, hb, M, H, D, H / 128);
  // GEMM2: out = h @ w2^T + b2, [12544,768] f32 ; 49x6 = 294 blocks
  gemm_bt<false, false><<<(M / 256) * (D / 128), 256, 0, stream>>>(
      hb, w2q, b2, d_out, M, D, H, D / 128);
}

// Round 7
// 208.494 us; speedup vs baseline: 1.1139x; 1.0691x over previous
//
#include <hip/hip_runtime.h>
#include <hip/hip_bf16.h>
#include <stdint.h>

typedef __attribute__((ext_vector_type(8))) short bf16x8;
typedef __attribute__((ext_vector_type(4))) float f32x4;

__device__ __forceinline__ unsigned short f2bf(float f) {
  __hip_bfloat16 h = __float2bfloat16(f);
  return *reinterpret_cast<unsigned short*>(&h);
}

// ---------------- absmax over both weights (gridDim.y = tensor id) ----------------
__global__ void absmax2_kernel(const float* __restrict__ w1, const float* __restrict__ w2,
                               int n4, unsigned int* __restrict__ out) {
  const float* w = blockIdx.y ? w2 : w1;
  __shared__ unsigned int red[256];
  unsigned int m = 0u;
  const uint4* w4 = reinterpret_cast<const uint4*>(w);
  for (int i = blockIdx.x * blockDim.x + threadIdx.x; i < n4;
       i += gridDim.x * blockDim.x) {
    uint4 v = w4[i];
    m = max(m, v.x & 0x7fffffffu);
    m = max(m, v.y & 0x7fffffffu);
    m = max(m, v.z & 0x7fffffffu);
    m = max(m, v.w & 0x7fffffffu);
  }
  red[threadIdx.x] = m;
  __syncthreads();
  for (int s = 128; s > 0; s >>= 1) {
    if ((int)threadIdx.x < s)
      red[threadIdx.x] = max(red[threadIdx.x], red[threadIdx.x + s]);
    __syncthreads();
  }
  if (threadIdx.x == 0) atomicMax(out + blockIdx.y, red[0]);
}

// ---------------- fused: fake-quant w1/w2 (y=0/1) + cast x (y=2), all -> bf16 ----------------
__global__ void quantcast_kernel(const float* __restrict__ w1, const float* __restrict__ w2,
                                 const float* __restrict__ x,
                                 int n4w, int n4x,
                                 const unsigned int* __restrict__ maxbits,
                                 const int* __restrict__ bits,
                                 unsigned short* __restrict__ o1,
                                 unsigned short* __restrict__ o2,
                                 unsigned short* __restrict__ ox) {
  if (blockIdx.y == 2) {
    const float4* x4 = reinterpret_cast<const float4*>(x);
    ushort4* o4 = reinterpret_cast<ushort4*>(ox);
    for (int i = blockIdx.x * blockDim.x + threadIdx.x; i < n4x;
         i += gridDim.x * blockDim.x) {
      float4 v = x4[i];
      o4[i] = make_ushort4(f2bf(v.x), f2bf(v.y), f2bf(v.z), f2bf(v.w));
    }
    return;
  }
  const float* w = blockIdx.y ? w2 : w1;
  unsigned short* o = blockIdx.y ? o2 : o1;
  const float qmax = (float)((1 << (*bits - 1)) - 1);
  const float scale = __uint_as_float(maxbits[blockIdx.y]) / qmax;
  const float4* w4 = reinterpret_cast<const float4*>(w);
  ushort4* o4 = reinterpret_cast<ushort4*>(o);
  for (int i = blockIdx.x * blockDim.x + threadIdx.x; i < n4w;
       i += gridDim.x * blockDim.x) {
    float4 v = w4[i];
    float a = fminf(fmaxf(rintf(v.x / scale), -qmax), qmax) * scale;
    float b = fminf(fmaxf(rintf(v.y / scale), -qmax), qmax) * scale;
    float c = fminf(fmaxf(rintf(v.z / scale), -qmax), qmax) * scale;
    float d = fminf(fmaxf(rintf(v.w / scale), -qmax), qmax) * scale;
    o4[i] = make_ushort4(f2bf(a), f2bf(b), f2bf(c), f2bf(d));
  }
}

// ---------------- 8-wave pipelined 256x256 bf16 GEMM (T2+T3+T4+T5) ----------------
// C[M,N] = A[M,K] * B[N,K]^T + bias, optional ReLU.
// 512 threads = 8 waves (2M x 4N), wave tile 128x64. BK=64 as 2 khalves of 32.
// LDS (dynamic 128KB): A[2 dbuf][2 kh][256][32], B same at +32768 elems.
// 4 phases/K-tile: (kstep,mseg). Per phase: 1 khalf stage (2 global_load_lds)
//   -> [counted vmcnt at p0/p2 only] -> s_barrier -> ds_read (8 or 4 b128)
//   -> lgkmcnt(0)+sched_barrier -> setprio(1) 16 MFMA setprio(0) -> s_barrier.
// Stage map: p0:Akh1(t+1)  p1:Bkh1(t+1)  p2:Akh0(t+2)  p3:Bkh0(t+2).
//   (each region restaged >=1 full barrier-pair after its last read)
// Ledger (2 instr per khalf stage): steady vmcnt(10) at p0/p2; tails 4/8/0.
// Swizzle (T2, rule 21): LDS linear; global source slot ^= (row>>1)&3; same
// XOR on ds_read (rounds 3-6 measured: 0 bank conflicts).
template<bool RELU, bool BF16_OUT>
__global__ __launch_bounds__(512, 2)
void gemm8w(const unsigned short* __restrict__ A,  // [M,K] bf16 bits
            const unsigned short* __restrict__ B,  // [N,K] bf16 bits
            const float* __restrict__ bias,        // [N]
            void* __restrict__ Cout,               // [M,N] bf16 or f32
            int M, int N, int K, int gx) {
  extern __shared__ unsigned short lds[];  // A: [0,32768) ; B: [32768,65536)

  // bijective XCD swizzle (T1/m204)
  const int nwg = gridDim.x;
  const int orig = blockIdx.x;
  const int q = nwg >> 3, r = nwg & 7;
  const int xcd = orig & 7, cidx = orig >> 3;
  const int wgid = (xcd < r ? xcd * (q + 1) : r * (q + 1) + (xcd - r) * q) + cidx;
  const int bx = wgid % gx;
  const int by = wgid / gx;

  const int tid = threadIdx.x;
  const int lane = tid & 63;
  const int wave = tid >> 6;
  const int wr = wave >> 2;   // 0..1 : 128-row band
  const int wc = wave & 3;    // 0..3 : 64-col band
  const long brow = (long)by * 256;
  const long bcol = (long)bx * 256;

  f32x4 acc[8][4] = {};

  const int fr = lane & 15;
  const int fq = lane >> 4;                            // 16B k-slot 0..3
  const int swz8 = ((lane & 3) ^ ((lane >> 3) & 3)) * 8;  // staging src slot
  const int sgrow = wave * 16 + (lane >> 2);           // staging row in 128-chunk

  // one khalf stage = 2 cooperative loads (each: 512 thr x 16B = 128 rows)
  auto SA = [&](int t, int kh) {
    unsigned short* dst = lds + ((t & 1) * 2 + kh) * 8192 + wave * 16 * 32;
    const unsigned short* g = A + (brow + sgrow) * (long)K + t * 64 + kh * 32 + swz8;
#pragma unroll
    for (int c = 0; c < 2; ++c)
      __builtin_amdgcn_global_load_lds(
          (const __attribute__((address_space(1))) void*)(g + (long)c * 128 * K),
          (__attribute__((address_space(3))) void*)(dst + c * 128 * 32), 16, 0, 0);
  };
  auto SB = [&](int t, int kh) {
    unsigned short* dst = lds + 32768 + ((t & 1) * 2 + kh) * 8192 + wave * 16 * 32;
    const unsigned short* g = B + (bcol + sgrow) * (long)K + t * 64 + kh * 32 + swz8;
#pragma unroll
    for (int c = 0; c < 2; ++c)
      __builtin_amdgcn_global_load_lds(
          (const __attribute__((address_space(1))) void*)(g + (long)c * 128 * K),
          (__attribute__((address_space(3))) void*)(dst + c * 128 * 32), 16, 0, 0);
  };

  auto RDA = [&](int b, int ks, int mseg, bf16x8* a) {
    const unsigned short* base = lds + (b * 2 + ks) * 8192;
#pragma unroll
    for (int mi = 0; mi < 4; ++mi) {
      const int row = wr * 128 + mseg * 64 + mi * 16 + fr;
      a[mi] = *reinterpret_cast<const bf16x8*>(base + row * 32 + ((fq ^ ((row >> 1) & 3)) * 8));
    }
  };
  auto RDB = [&](int b, int ks, bf16x8* bb) {
    const unsigned short* base = lds + 32768 + (b * 2 + ks) * 8192;
#pragma unroll
    for (int ni = 0; ni < 4; ++ni) {
      const int row = wc * 64 + ni * 16 + fr;
      bb[ni] = *reinterpret_cast<const bf16x8*>(base + row * 32 + ((fq ^ ((row >> 1) & 3)) * 8));
    }
  };
  auto MM = [&](int mseg, bf16x8* a, bf16x8* bb) {
#pragma unroll
    for (int mi = 0; mi < 4; ++mi)
#pragma unroll
      for (int ni = 0; ni < 4; ++ni)
        acc[mseg * 4 + mi][ni] = __builtin_amdgcn_mfma_f32_16x16x32_bf16(
            a[mi], bb[ni], acc[mseg * 4 + mi][ni], 0, 0, 0);
  };

  const int nt = K / 64;
  // prologue: tile0 fully, tile1 kh0 (order fixes the ledger)
  SA(0, 0); SB(0, 0); SA(0, 1); SB(0, 1); SA(1, 0); SB(1, 0);

  bf16x8 a[4], bb[4];
  for (int t = 0; t < nt; ++t) {
    const int b = t & 1;
    // ---- P0: kstep0, mseg0 ----
    if (t + 1 < nt) {
      SA(t + 1, 1);
      asm volatile("s_waitcnt vmcnt(10)" ::: "memory");
    } else {
      asm volatile("s_waitcnt vmcnt(4)" ::: "memory");
    }
    asm volatile("s_barrier" ::: "memory");
    RDA(b, 0, 0, a); RDB(b, 0, bb);
    asm volatile("s_waitcnt lgkmcnt(0)" ::: "memory");
    __builtin_amdgcn_sched_barrier(0);
    __builtin_amdgcn_s_setprio(1);
    MM(0, a, bb);
    __builtin_amdgcn_s_setprio(0);
    asm volatile("s_barrier" ::: "memory");
    // ---- P1: kstep0, mseg1 (reuse bb) ----
    if (t + 1 < nt) SB(t + 1, 1);
    RDA(b, 0, 1, a);
    asm volatile("s_waitcnt lgkmcnt(0)" ::: "memory");
    __builtin_amdgcn_sched_barrier(0);
    __builtin_amdgcn_s_setprio(1);
    MM(1, a, bb);
    __builtin_amdgcn_s_setprio(0);
    asm volatile("s_barrier" ::: "memory");
    // ---- P2: kstep1, mseg0 ----
    if (t + 2 < nt) SA(t + 2, 0);
    if (t + 3 <= nt)      asm volatile("s_waitcnt vmcnt(10)" ::: "memory");
    else if (t == nt - 2) asm volatile("s_waitcnt vmcnt(8)"  ::: "memory");
    else                  asm volatile("s_waitcnt vmcnt(0)"  ::: "memory");
    asm volatile("s_barrier" ::: "memory");
    RDA(b, 1, 0, a); RDB(b, 1, bb);
    asm volatile("s_waitcnt lgkmcnt(0)" ::: "memory");
    __builtin_amdgcn_sched_barrier(0);
    __builtin_amdgcn_s_setprio(1);
    MM(0, a, bb);
    __builtin_amdgcn_s_setprio(0);
    asm volatile("s_barrier" ::: "memory");
    // ---- P3: kstep1, mseg1 (reuse bb) ----
    if (t + 2 < nt) SB(t + 2, 0);
    RDA(b, 1, 1, a);
    asm volatile("s_waitcnt lgkmcnt(0)" ::: "memory");
    __builtin_amdgcn_sched_barrier(0);
    __builtin_amdgcn_s_setprio(1);
    MM(1, a, bb);
    __builtin_amdgcn_s_setprio(0);
    asm volatile("s_barrier" ::: "memory");
  }

  // epilogue: C/D layout col=lane&15, row=(lane>>4)*4+rr  [m89/m91 verified]
#pragma unroll
  for (int ni = 0; ni < 4; ++ni) {
    const long col = bcol + wc * 64 + ni * 16 + fr;
    const float bv = bias[col];
#pragma unroll
    for (int mi = 0; mi < 8; ++mi) {
#pragma unroll
      for (int rr = 0; rr < 4; ++rr) {
        const long row = brow + wr * 128 + mi * 16 + fq * 4 + rr;
        float v = acc[mi][ni][rr] + bv;
        if (RELU) v = fmaxf(v, 0.0f);
        if (BF16_OUT)
          ((unsigned short*)Cout)[row * N + col] = f2bf(v);
        else
          ((float*)Cout)[row * N + col] = v;
      }
    }
  }
}

extern "C" void kernel_launch(void* const* d_in, const int* in_sizes, int n_in,
                              void* d_out, int out_size, void* d_ws, size_t ws_size,
                              hipStream_t stream) {
  const float* x  = (const float*)d_in[0];
  const float* w1 = (const float*)d_in[1];
  const float* b1 = (const float*)d_in[2];
  const float* w2 = (const float*)d_in[3];
  const float* b2 = (const float*)d_in[4];
  const int* bits = (const int*)d_in[5];

  const int M = 64 * 196;  // 12544 tokens
  const int D = 768, H = 3072;
  const int nx = M * D;
  const int nw1 = H * D;

  char* ws = (char*)d_ws;
  unsigned int* scales = (unsigned int*)ws;
  unsigned short* xb  = (unsigned short*)(ws + 256);
  unsigned short* w1q = (unsigned short*)(ws + 256 + (size_t)nx * 2);
  unsigned short* w2q = (unsigned short*)(ws + 256 + (size_t)nx * 2 + (size_t)nw1 * 2);
  unsigned short* hb  = (unsigned short*)(ws + 256 + (size_t)nx * 2 + (size_t)nw1 * 4);

  // allow 128KB dynamic LDS (idempotent, host-side, capture-safe)
  static bool attr_done = false;
  if (!attr_done) {
    hipFuncSetAttribute((const void*)gemm8w<true, true>,
                        hipFuncAttributeMaxDynamicSharedMemorySize, 131072);
    hipFuncSetAttribute((const void*)gemm8w<false, false>,
                        hipFuncAttributeMaxDynamicSharedMemorySize, 131072);
    attr_done = true;
  }

  hipMemsetAsync(scales, 0, 8, stream);
  absmax2_kernel<<<dim3(512, 2), 256, 0, stream>>>(w1, w2, nw1 / 4, scales);
  quantcast_kernel<<<dim3(768, 3), 256, 0, stream>>>(w1, w2, x, nw1 / 4, nx / 4,
                                                     scales, bits, w1q, w2q, xb);

  // GEMM1: h = relu(x @ w1^T + b1), [12544,3072] bf16 ; 49x12 = 588 blocks, nt=12
  gemm8w<true, true><<<(M / 256) * (H / 256), 512, 131072, stream>>>(
      xb, w1q, b1, hb, M, H, D, H / 256);
  // GEMM2: out = h @ w2^T + b2, [12544,768] f32 ; 49x3 = 147 blocks, nt=48
  gemm8w<false, false><<<(M / 256) * (D / 256), 512, 131072, stream>>>(
      hb, w2q, b2, d_out, M, D, H, D / 256);
}